// Round 12
// baseline (451.138 us; speedup 1.0000x reference)
//
#include <hip/hip_runtime.h>
#include <math.h>

// SNN forward, fused. Inputs f32, output f32 [2048][200].
// R12 = R11 + compile fix (cvt_pkrtz returns __fp16x2, not _Float16x2).
// THREE batch elements per block (weights shared: 128 regs; per-elem state
// ~36 -> ~235 regs, 2 waves/SIMD, 6 elems in flight/CU, 3-way ILP in every
// serial chain). sc scratch is F16 (cvt_pkrtz pack): 3*10.2KB sc +
// 3*15.4KB bits(+xa alias) = 77KB LDS -> 2 blocks/CU. Barrier-free hidden
// layers (wave-local cols, bits ping-pong, 1 barrier/layer).
// grid=683 x 256 thr (tail block guards elem 2048).

#define T_N 150
#define DIN 20
#define H 256
#define NOUT 200
#define NMT 10
#define NE 3               // elems per block
#define SCH 20             // sc col stride in f16 shorts (16 rows + 4 pad)
#define XAP 24             // xa row stride (bf16 shorts) = BW dwords
#define BW 12              // bits row stride (dwords), 48B -> 16B-aligned rows
#define BITN (160 * BW + 8)

#define WS_W1 0
#define WS_W2 5120
#define WS_W3 70656
#define WS_W4 136192
#define WS_WO 201728
#define WS_TOT 252928

typedef short s16x8 __attribute__((ext_vector_type(8)));
typedef float f32x4 __attribute__((ext_vector_type(4)));
typedef unsigned int u32x4 __attribute__((ext_vector_type(4)));
typedef unsigned int u32x2 __attribute__((ext_vector_type(2)));
typedef __fp16 fp16x2 __attribute__((ext_vector_type(2)));

__device__ __forceinline__ unsigned short f2bf(float f) {
  union { float f; unsigned int i; } v; v.f = f;
  unsigned int r = v.i + 0x7FFFu + ((v.i >> 16) & 1u);
  return (unsigned short)(r >> 16);
}
__device__ __forceinline__ unsigned pk2(float a, float b) {
  union { fp16x2 h; unsigned u; } cv;
  cv.h = __builtin_amdgcn_cvt_pkrtz(a, b);
  return cv.u;
}
__device__ __forceinline__ float uph(unsigned short s) {
  union { unsigned short s; _Float16 h; } c; c.s = s; return (float)c.h;
}

__global__ void cvt_weights(const float* __restrict__ W1, const float* __restrict__ W2,
                            const float* __restrict__ W3, const float* __restrict__ W4,
                            const float* __restrict__ Wo, unsigned short* __restrict__ ws) {
  int idx = blockIdx.x * blockDim.x + threadIdx.x;
  int stride = gridDim.x * blockDim.x;
  for (int i = idx; i < WS_TOT; i += stride) {
    float v;
    if (i < WS_W2)      v = W1[i - WS_W1];
    else if (i < WS_W3) v = W2[i - WS_W2];
    else if (i < WS_W4) v = W3[i - WS_W3];
    else if (i < WS_WO) v = W4[i - WS_W4];
    else                v = Wo[i - WS_WO];
    ws[i] = f2bf(v);
  }
}

// expand 8 spike bits (byte t) -> packed-bf16 x8 fragment (0.0 / 1.0)
__device__ __forceinline__ s16x8 expand8(unsigned int t) {
  unsigned int r2 = t * 0x8001u;
  u32x4 d;
  d[0] = (r2 & 0x00010001u) * 0x3F80u;
  d[1] = (r2 & 0x00040004u) * 0x0FE0u;
  d[2] = (r2 & 0x00100010u) * 0x03F8u;
  d[3] = (r2 & 0x00400040u) * 0x00FEu;
  union { u32x4 u; s16x8 s; } cv; cv.u = d;
  return cv.s;
}

__global__ __launch_bounds__(256, 2) void snn_fused(
    const float* __restrict__ x,             // [2048][150][20] f32
    const unsigned short* __restrict__ wsb,  // bf16 weights (d_ws)
    const float* __restrict__ b1,            // [256] f32
    const float* __restrict__ b2,
    const float* __restrict__ b3,
    const float* __restrict__ b4,
    float* __restrict__ out)                 // [2048][200] f32
{
  __shared__ unsigned short scb[NE][256 * SCH];  // 30720 B: f16 C scratch
  __shared__ unsigned int ubits[NE][2][BITN];    // 46272 B: spike bits, ping-pong
                                                 // total 76992 B -> 2 blocks/CU

  const int tid  = threadIdx.x;
  const int lane = tid & 63;
  const int wave = tid >> 6;    // 0..3
  const int c16  = lane & 15;
  const int quad = lane >> 4;
  const int shq  = quad * 8;
  const int colw = 64 * wave;   // wave owns cols [64w, 64w+64)
  const int cb   = colw + c16;
  const int ge0  = NE * (int)blockIdx.x;

  float m[NE];
  bool  sp[NE];

  auto store3 = [&](f32x4 (&c)[NE][4]) {
    #pragma unroll
    for (int e = 0; e < NE; ++e) {
      #pragma unroll
      for (int i = 0; i < 4; ++i) {
        u32x2 w = { pk2(c[e][i][0], c[e][i][1]), pk2(c[e][i][2], c[e][i][3]) };
        *(u32x2*)&scb[e][(cb + 16 * i) * SCH + quad * 4] = w;
      }
    }
  };

  // membrane scan of tile mt (nrows valid rows), all 3 elems interleaved.
  // Wave-local: reads only this wave's sc cols; full 64-bit ballot = this
  // wave's 2 dwords of the 256-bit row mask.
  auto scan3 = [&](int mt, int nrows, unsigned int* w0, unsigned int* w1,
                   unsigned int* w2) {
    unsigned int* wb[NE] = {w0, w1, w2};
    u32x2 d[NE][4];
    #pragma unroll
    for (int e = 0; e < NE; ++e) {
      const u32x2* p = (const u32x2*)&scb[e][(colw + lane) * SCH];
      #pragma unroll
      for (int j = 0; j < 4; ++j) d[e][j] = p[j];
    }
    unsigned long long keep[NE] = {0ull, 0ull, 0ull};
    #pragma unroll
    for (int r = 0; r < 16; ++r) {
      if (r < nrows) {
        #pragma unroll
        for (int e = 0; e < NE; ++e) {
          union { unsigned u; _Float16 h[2]; } cu;
          cu.u = d[e][r >> 2][(r >> 1) & 1];
          float inp = (float)cu.h[r & 1];
          float rs = sp[e] ? 1.0f : 0.0f;
          m[e] = 0.9f * m[e] + (inp - rs);
          sp[e] = m[e] > 1.0f;
          unsigned long long msk = __ballot(sp[e]);
          if (lane == r) keep[e] = msk;
        }
      }
    }
    if (lane < 16) {
      #pragma unroll
      for (int e = 0; e < NE; ++e)
        *(unsigned long long*)&wb[e][(mt * 16 + lane) * BW + 2 * wave] = keep[e];
    }
  };

  auto loadmasks3 = [&](int mt, const unsigned int* r0, const unsigned int* r1,
                        const unsigned int* r2, unsigned int (&rm)[NE][8]) {
    const unsigned int* bb[NE] = {r0, r1, r2};
    #pragma unroll
    for (int e = 0; e < NE; ++e) {
      const unsigned int* bp = &bb[e][(mt * 16 + c16) * BW];
      u32x4 p0 = *(const u32x4*)bp;
      u32x4 p1 = *(const u32x4*)(bp + 4);
      rm[e][0] = p0[0]; rm[e][1] = p0[1]; rm[e][2] = p0[2]; rm[e][3] = p0[3];
      rm[e][4] = p1[0]; rm[e][5] = p1[1]; rm[e][6] = p1[2]; rm[e][7] = p1[3];
    }
  };

  // ---- init: zero both bits buffers (covers xa pads + tail rows) ----
  for (int i = tid; i < NE * 2 * BITN; i += 256) ((unsigned int*)ubits)[i] = 0;
  __syncthreads();
  #pragma unroll
  for (int e = 0; e < NE; ++e) {
    int ge = ge0 + e; if (ge > 2047) ge = 2047;   // tail clamp (store guarded)
    const float* xb = x + (size_t)ge * (T_N * DIN);
    unsigned short* xa = (unsigned short*)&ubits[e][1][0];
    for (int i = tid; i < T_N * DIN; i += 256) {
      int t = i / DIN, j = i - t * DIN;
      xa[t * XAP + j] = f2bf(xb[i]);
    }
  }

  // ---- layer 1: x @ W1^T (K=20 pad 32) -> ubits[e][0]; barrier-free ----
  {
    s16x8 w1f[4];
    #pragma unroll
    for (int i = 0; i < 4; ++i) {
      int n = cb + 16 * i;
      #pragma unroll
      for (int j = 0; j < 8; ++j) {
        int k = shq + j;
        w1f[i][j] = (k < DIN) ? (short)wsb[WS_W1 + n * DIN + k] : (short)0;
      }
      asm volatile("" : "+v"(w1f[i]));
    }
    float bc[4];
    #pragma unroll
    for (int i = 0; i < 4; ++i) bc[i] = b1[cb + 16 * i];
    #pragma unroll
    for (int e = 0; e < NE; ++e) { m[e] = 0.0f; sp[e] = false; }
    __syncthreads();  // xa staged
    for (int mt = 0; mt < NMT; ++mt) {
      s16x8 a[NE];
      #pragma unroll
      for (int e = 0; e < NE; ++e) {
        const unsigned short* xa = (const unsigned short*)&ubits[e][1][0];
        a[e] = *(const s16x8*)&xa[(mt * 16 + c16) * XAP + shq];
      }
      f32x4 c[NE][4];
      #pragma unroll
      for (int e = 0; e < NE; ++e)
        #pragma unroll
        for (int i = 0; i < 4; ++i) {
          f32x4 z = {bc[i], bc[i], bc[i], bc[i]}; c[e][i] = z;
        }
      #pragma unroll
      for (int e = 0; e < NE; ++e)
        #pragma unroll
        for (int i = 0; i < 4; ++i)
          c[e][i] = __builtin_amdgcn_mfma_f32_16x16x32_bf16(a[e], w1f[i], c[e][i], 0, 0, 0);
      if (mt > 0) scan3(mt - 1, 16, &ubits[0][0][0], &ubits[1][0][0], &ubits[2][0][0]);
      store3(c);
    }
    scan3(9, 6, &ubits[0][0][0], &ubits[1][0][0], &ubits[2][0][0]);  // rows 144-149
  }
  __syncthreads();  // bits buf 0 complete

  // ---- layers 2..4: barrier-free, bits ping-pong ----
  const float* bsl[3] = {b2, b3, b4};
  const int wofs[3] = {WS_W2, WS_W3, WS_W4};
  for (int l = 0; l < 3; ++l) {
    const unsigned short* wl = wsb + wofs[l];
    const int rp = l & 1, wp = rp ^ 1;
    s16x8 wf[4][8];
    #pragma unroll
    for (int i = 0; i < 4; ++i) {
      int n = cb + 16 * i;
      #pragma unroll
      for (int ks = 0; ks < 8; ++ks) {
        wf[i][ks] = *(const s16x8*)(wl + n * H + ks * 32 + shq);
        asm volatile("" : "+v"(wf[i][ks]));
      }
    }
    float bc[4];
    #pragma unroll
    for (int i = 0; i < 4; ++i) bc[i] = bsl[l][cb + 16 * i];
    #pragma unroll
    for (int e = 0; e < NE; ++e) { m[e] = 0.0f; sp[e] = false; }
    for (int mt = 0; mt < NMT; ++mt) {
      unsigned int rm[NE][8];
      loadmasks3(mt, &ubits[0][rp][0], &ubits[1][rp][0], &ubits[2][rp][0], rm);
      f32x4 c[NE][4];
      #pragma unroll
      for (int e = 0; e < NE; ++e)
        #pragma unroll
        for (int i = 0; i < 4; ++i) {
          f32x4 z = {bc[i], bc[i], bc[i], bc[i]}; c[e][i] = z;
        }
      #pragma unroll
      for (int ks = 0; ks < 8; ++ks) {
        #pragma unroll
        for (int e = 0; e < NE; ++e) {
          s16x8 a = expand8((rm[e][ks] >> shq) & 0xFFu);
          #pragma unroll
          for (int i = 0; i < 4; ++i)
            c[e][i] = __builtin_amdgcn_mfma_f32_16x16x32_bf16(a, wf[i][ks], c[e][i], 0, 0, 0);
        }
      }
      if (mt > 0) scan3(mt - 1, 16, &ubits[0][wp][0], &ubits[1][wp][0], &ubits[2][wp][0]);
      store3(c);
    }
    scan3(9, 6, &ubits[0][wp][0], &ubits[1][wp][0], &ubits[2][wp][0]);
    __syncthreads();  // bits buf wp complete
  }

  // ---- output layer (reads ubits[e][1]): GEMM + mo-scan + softmax (t>50) ----
  {
    s16x8 wo[4][8];
    #pragma unroll
    for (int i = 0; i < 4; ++i) {
      int n = cb + 16 * i;
      bool valid = (n < NOUT);
      #pragma unroll
      for (int ks = 0; ks < 8; ++ks) {
        s16x8 z = {0, 0, 0, 0, 0, 0, 0, 0};
        wo[i][ks] = valid ? *(const s16x8*)(wsb + WS_WO + n * H + ks * 32 + shq) : z;
        asm volatile("" : "+v"(wo[i][ks]));
      }
    }

    float mo[NE] = {0.f, 0.f, 0.f};
    float acc[NE][4] = {};

    auto moscan3 = [&](int mt) {
      if (tid < 208) {
        #pragma unroll
        for (int e = 0; e < NE; ++e) {
          u32x2* p = (u32x2*)&scb[e][tid * SCH];
          u32x2 d[4];
          #pragma unroll
          for (int j = 0; j < 4; ++j) d[j] = p[j];
          #pragma unroll
          for (int r = 0; r < 16; ++r) {
            int t = mt * 16 + r;
            if (t < T_N) {
              union { unsigned u; _Float16 h[2]; } cu;
              cu.u = d[r >> 2][(r >> 1) & 1];
              float inp = (float)cu.h[r & 1];
              float reset = (mo[e] > 1.0f) ? 1.0f : 0.0f;
              mo[e] = 0.9f * mo[e] + inp - reset;
              cu.h[r & 1] = (_Float16)mo[e];
              d[r >> 2][(r >> 1) & 1] = cu.u;
            }
          }
          #pragma unroll
          for (int j = 0; j < 4; ++j) p[j] = d[j];
        }
      }
    };
    auto softmax3 = [&](int mt) {
      #pragma unroll
      for (int rr = 0; rr < 4; ++rr) {
        int r = 4 * wave + rr;
        int t = mt * 16 + r;
        if (t > 50 && t < T_N) {        // wave-uniform
          #pragma unroll
          for (int e = 0; e < NE; ++e) {
            const unsigned short* sh = &scb[e][0];
            float v0 = uph(sh[lane * SCH + r]);
            float v1 = uph(sh[(64 + lane) * SCH + r]);
            float v2 = uph(sh[(128 + lane) * SCH + r]);
            bool has3 = (lane < 8);      // n=192+lane valid only for n<200
            float v3 = has3 ? uph(sh[(192 + lane) * SCH + r]) : -INFINITY;
            float mx = fmaxf(fmaxf(v0, v1), fmaxf(v2, v3));
            #pragma unroll
            for (int dd = 32; dd >= 1; dd >>= 1) mx = fmaxf(mx, __shfl_xor(mx, dd));
            float e0 = __expf(v0 - mx), e1 = __expf(v1 - mx), e2 = __expf(v2 - mx);
            float e3 = has3 ? __expf(v3 - mx) : 0.0f;
            float s = e0 + e1 + e2 + e3;
            #pragma unroll
            for (int dd = 32; dd >= 1; dd >>= 1) s += __shfl_xor(s, dd);
            float inv = 1.0f / s;
            acc[e][0] += e0 * inv; acc[e][1] += e1 * inv;
            acc[e][2] += e2 * inv; acc[e][3] += e3 * inv;
          }
        }
      }
    };

    for (int mt = 0; mt < NMT; ++mt) {
      unsigned int rm[NE][8];
      loadmasks3(mt, &ubits[0][1][0], &ubits[1][1][0], &ubits[2][1][0], rm);
      f32x4 c[NE][4];
      #pragma unroll
      for (int e = 0; e < NE; ++e)
        #pragma unroll
        for (int i = 0; i < 4; ++i) { f32x4 z = {0.f, 0.f, 0.f, 0.f}; c[e][i] = z; }
      #pragma unroll
      for (int ks = 0; ks < 8; ++ks) {
        #pragma unroll
        for (int e = 0; e < NE; ++e) {
          s16x8 a = expand8((rm[e][ks] >> shq) & 0xFFu);
          #pragma unroll
          for (int i = 0; i < 4; ++i)
            c[e][i] = __builtin_amdgcn_mfma_f32_16x16x32_bf16(a, wo[i][ks], c[e][i], 0, 0, 0);
        }
      }
      __syncthreads();              // prior softmax done reading sc
      store3(c);
      __syncthreads();              // C complete (cross-wave)
      moscan3(mt);
      __syncthreads();              // membranes written (cross-wave)
      softmax3(mt);
    }
    __syncthreads();

    // merge 4 per-wave accumulators per elem (scb reused as f32), store
    #pragma unroll
    for (int e = 0; e < NE; ++e) {
      float* fs = (float*)&scb[e][0];
      fs[wave * 260 + lane]       = acc[e][0];
      fs[wave * 260 + 64 + lane]  = acc[e][1];
      fs[wave * 260 + 128 + lane] = acc[e][2];
      if (lane < 8) fs[wave * 260 + 192 + lane] = acc[e][3];
    }
    __syncthreads();
    if (tid < NOUT) {
      #pragma unroll
      for (int e = 0; e < NE; ++e) {
        int ge = ge0 + e;
        if (ge < 2048) {
          const float* fs = (const float*)&scb[e][0];
          float v = fs[tid] + fs[260 + tid] + fs[520 + tid] + fs[780 + tid];
          out[(size_t)ge * NOUT + tid] = v;
        }
      }
    }
  }
}

extern "C" void kernel_launch(void* const* d_in, const int* in_sizes, int n_in,
                              void* d_out, int out_size, void* d_ws, size_t ws_size,
                              hipStream_t stream) {
  (void)in_sizes; (void)n_in; (void)ws_size; (void)out_size;
  unsigned short* wsb = (unsigned short*)d_ws;
  cvt_weights<<<256, 256, 0, stream>>>(
      (const float*)d_in[1], (const float*)d_in[3], (const float*)d_in[5],
      (const float*)d_in[7], (const float*)d_in[9], wsb);
  snn_fused<<<683, 256, 0, stream>>>(   // ceil(2048/3)
      (const float*)d_in[0], wsb,
      (const float*)d_in[2], (const float*)d_in[4],
      (const float*)d_in[6], (const float*)d_in[8],
      (float*)d_out);
}

// Round 13
// 389.966 us; speedup vs baseline: 1.1569x; 1.1569x over previous
//
#include <hip/hip_runtime.h>
#include <math.h>

// SNN forward, fused. Inputs f32, output f32 [2048][200].
// R13 = R10 (best, 339us) + two stall cuts:
//  (a) scan split into phase-A (pure serial fma/cmp/cndmask recurrence,
//      membranes kept in registers) and phase-B (16 batched ballots at tile
//      end) -- removes cross-lane SALU syncs from inside the serial chain.
//  (b) OUT phase: 2 barriers/tile instead of 3 (store->moscan is wave-local).
// Config: NE=2 elems/block, 256 thr (4 waves x 64 cols), grid=1024 (2 exact
// rounds of 512 resident blocks), weights pinned (128 VGPR), 72KB LDS,
// 2 blocks/CU, barrier-free hidden layers (bits ping-pong, 1 barrier/layer).

#define T_N 150
#define DIN 20
#define H 256
#define NOUT 200
#define NMT 10
#define CST 20             // sc col stride (f32): 16 rows + 4 pad
#define SCB 5120           // per-elem sc buffer (f32) = 256 cols * CST
#define XAP 24             // xa row stride (bf16): 20 data + 4 zero pad
#define BW 12              // bits row stride (dwords)
#define BITN (160 * BW + 8)  // per bits buffer (+8 dword tail pad)

#define WS_W1 0
#define WS_W2 5120
#define WS_W3 70656
#define WS_W4 136192
#define WS_WO 201728
#define WS_TOT 252928

typedef short s16x8 __attribute__((ext_vector_type(8)));
typedef float f32x4 __attribute__((ext_vector_type(4)));
typedef unsigned int u32x4 __attribute__((ext_vector_type(4)));

__device__ __forceinline__ unsigned short f2bf(float f) {
  union { float f; unsigned int i; } v; v.f = f;
  unsigned int r = v.i + 0x7FFFu + ((v.i >> 16) & 1u);
  return (unsigned short)(r >> 16);
}

__global__ void cvt_weights(const float* __restrict__ W1, const float* __restrict__ W2,
                            const float* __restrict__ W3, const float* __restrict__ W4,
                            const float* __restrict__ Wo, unsigned short* __restrict__ ws) {
  int idx = blockIdx.x * blockDim.x + threadIdx.x;
  int stride = gridDim.x * blockDim.x;
  for (int i = idx; i < WS_TOT; i += stride) {
    float v;
    if (i < WS_W2)      v = W1[i - WS_W1];
    else if (i < WS_W3) v = W2[i - WS_W2];
    else if (i < WS_W4) v = W3[i - WS_W3];
    else if (i < WS_WO) v = W4[i - WS_W4];
    else                v = Wo[i - WS_WO];
    ws[i] = f2bf(v);
  }
}

// expand 8 spike bits (byte t) -> packed-bf16 x8 fragment (0.0 / 1.0)
__device__ __forceinline__ s16x8 expand8(unsigned int t) {
  unsigned int r2 = t * 0x8001u;   // bit 2j -> pos 2j ; bit 2j+1 -> pos 16+2j
  u32x4 d;
  d[0] = (r2 & 0x00010001u) * 0x3F80u;
  d[1] = (r2 & 0x00040004u) * 0x0FE0u;
  d[2] = (r2 & 0x00100010u) * 0x03F8u;
  d[3] = (r2 & 0x00400040u) * 0x00FEu;
  union { u32x4 u; s16x8 s; } cv; cv.u = d;
  return cv.s;
}

__global__ __launch_bounds__(256, 2) void snn_fused(
    const float* __restrict__ x,             // [2048][150][20] f32
    const unsigned short* __restrict__ wsb,  // bf16 weights (d_ws)
    const float* __restrict__ b1,            // [256] f32
    const float* __restrict__ b2,
    const float* __restrict__ b3,
    const float* __restrict__ b4,
    float* __restrict__ out)                 // [2048][200] f32
{
  __shared__ float sc[2 * SCB];                // 40960 B: per-elem C scratch
  __shared__ unsigned int ubits[2][2][BITN];   // 30976 B: per-elem bits, ping-pong
                                               // total 71936 B -> 2 blocks/CU

  const int tid  = threadIdx.x;
  const int lane = tid & 63;
  const int wave = tid >> 6;    // 0..3
  const int c16  = lane & 15;
  const int quad = lane >> 4;
  const int shq  = quad * 8;
  const int bidx = blockIdx.x;
  const int colw = 64 * wave;   // wave owns cols [64w, 64w+64)
  const int cb   = colw + c16;

  float* sc0 = sc;
  float* sc1 = sc + SCB;
  unsigned short* xa0 = (unsigned short*)&ubits[0][1][0];
  unsigned short* xa1 = (unsigned short*)&ubits[1][1][0];

  auto store_c = [&](float* scE, f32x4* c) {
    #pragma unroll
    for (int i = 0; i < 4; ++i)
      *(f32x4*)&scE[(cb + 16 * i) * CST + quad * 4] = c[i];
  };

  // membrane scan: phase A = serial recurrence (no cross-lane), phase B =
  // batched ballots. 64 lanes own the wave's 64 cols; wave-local sc.
  auto scan_tile = [&](int mt, const float* scE, float& m, bool& sp,
                       unsigned int* wb) {
    const f32x4* vp = (const f32x4*)&scE[(colw + lane) * CST];
    f32x4 v[4];
    #pragma unroll
    for (int j = 0; j < 4; ++j) v[j] = vp[j];
    // phase A: membranes back into v
    #pragma unroll
    for (int r = 0; r < 16; ++r) {
      int t = mt * 16 + r;
      if (t < T_N) {  // block-uniform
        float inp = v[r >> 2][r & 3];
        float sel = sp ? (inp - 1.0f) : inp;
        m = 0.9f * m + sel;
        sp = m > 1.0f;
        v[r >> 2][r & 3] = m;
      }
    }
    // phase B: batched ballots -> row masks
    unsigned long long keep = 0ull;
    #pragma unroll
    for (int r = 0; r < 16; ++r) {
      int t = mt * 16 + r;
      if (t < T_N) {
        unsigned long long msk = __ballot(v[r >> 2][r & 3] > 1.0f);
        if (lane == r) keep = msk;
      }
    }
    if (lane < 16)
      *(unsigned long long*)&wb[(mt * 16 + lane) * BW + 2 * wave] = keep;
  };

  auto load_masks = [&](const unsigned int* rb, int mt, unsigned int* rm) {
    const unsigned int* bp = &rb[(mt * 16 + c16) * BW];
    u32x4 a = *(const u32x4*)bp;
    u32x4 b = *(const u32x4*)(bp + 4);
    rm[0] = a[0]; rm[1] = a[1]; rm[2] = a[2]; rm[3] = a[3];
    rm[4] = b[0]; rm[5] = b[1]; rm[6] = b[2]; rm[7] = b[3];
  };

  // ---- init: zero xa regions (k-pad + tail rows), stage x as bf16 ----
  for (int i = tid; i < BITN; i += 256) { ubits[0][1][i] = 0; ubits[1][1][i] = 0; }
  __syncthreads();
  {
    const float* xb0 = x + (size_t)(2 * bidx) * (T_N * DIN);
    const float* xb1 = xb0 + (T_N * DIN);
    for (int i = tid; i < T_N * XAP; i += 256) {
      int t = i / XAP, j = i - t * XAP;
      unsigned short v0 = 0, v1 = 0;
      if (j < DIN) { v0 = f2bf(xb0[t * DIN + j]); v1 = f2bf(xb1[t * DIN + j]); }
      xa0[i] = v0; xa1[i] = v1;
    }
  }

  // ---- layer 1: x @ W1^T (K=20 pad 32) -> ubits[e][0]; barrier-free ----
  {
    s16x8 w1f[4];
    #pragma unroll
    for (int i = 0; i < 4; ++i) {
      int n = cb + 16 * i;
      #pragma unroll
      for (int j = 0; j < 8; ++j) {
        int k = shq + j;
        w1f[i][j] = (k < DIN) ? (short)wsb[WS_W1 + n * DIN + k] : (short)0;
      }
      asm volatile("" : "+v"(w1f[i]));
    }
    float bc[4];
    #pragma unroll
    for (int i = 0; i < 4; ++i) bc[i] = b1[cb + 16 * i];
    float m0 = 0.0f, m1 = 0.0f;
    bool sp0 = false, sp1 = false;
    __syncthreads();  // xa staged
    for (int mt = 0; mt < NMT; ++mt) {
      const s16x8 a0 = *(const s16x8*)&xa0[(mt * 16 + c16) * XAP + shq];
      const s16x8 a1 = *(const s16x8*)&xa1[(mt * 16 + c16) * XAP + shq];
      f32x4 c0[4], c1[4];
      #pragma unroll
      for (int i = 0; i < 4; ++i) {
        f32x4 z = {bc[i], bc[i], bc[i], bc[i]};
        c0[i] = z; c1[i] = z;
      }
      #pragma unroll
      for (int i = 0; i < 4; ++i) {
        c0[i] = __builtin_amdgcn_mfma_f32_16x16x32_bf16(a0, w1f[i], c0[i], 0, 0, 0);
        c1[i] = __builtin_amdgcn_mfma_f32_16x16x32_bf16(a1, w1f[i], c1[i], 0, 0, 0);
      }
      if (mt > 0) scan_tile(mt - 1, sc0, m0, sp0, ubits[0][0]);
      store_c(sc0, c0);
      if (mt > 0) scan_tile(mt - 1, sc1, m1, sp1, ubits[1][0]);
      store_c(sc1, c1);
    }
    scan_tile(9, sc0, m0, sp0, ubits[0][0]);
    scan_tile(9, sc1, m1, sp1, ubits[1][0]);
  }
  __syncthreads();  // bits buf 0 complete (both elems)

  // ---- layers 2..4: barrier-free, bits ping-pong per elem ----
  const float* bsl[3] = {b2, b3, b4};
  const int wofs[3] = {WS_W2, WS_W3, WS_W4};
  for (int l = 0; l < 3; ++l) {
    const unsigned short* wl = wsb + wofs[l];
    const int rp = l & 1, wp = rp ^ 1;
    s16x8 wf[4][8];
    #pragma unroll
    for (int i = 0; i < 4; ++i) {
      int n = cb + 16 * i;
      #pragma unroll
      for (int ks = 0; ks < 8; ++ks) {
        wf[i][ks] = *(const s16x8*)(wl + n * H + ks * 32 + shq);
        asm volatile("" : "+v"(wf[i][ks]));
      }
    }
    float bc[4];
    #pragma unroll
    for (int i = 0; i < 4; ++i) bc[i] = bsl[l][cb + 16 * i];
    float m0 = 0.0f, m1 = 0.0f;
    bool sp0 = false, sp1 = false;
    for (int mt = 0; mt < NMT; ++mt) {
      unsigned int rm0[8], rm1[8];
      load_masks(ubits[0][rp], mt, rm0);
      load_masks(ubits[1][rp], mt, rm1);
      f32x4 c0[4], c1[4];
      #pragma unroll
      for (int i = 0; i < 4; ++i) {
        f32x4 z = {bc[i], bc[i], bc[i], bc[i]};
        c0[i] = z; c1[i] = z;
      }
      #pragma unroll
      for (int ks = 0; ks < 8; ++ks) {
        s16x8 a0 = expand8((rm0[ks] >> shq) & 0xFFu);
        #pragma unroll
        for (int i = 0; i < 4; ++i)
          c0[i] = __builtin_amdgcn_mfma_f32_16x16x32_bf16(a0, wf[i][ks], c0[i], 0, 0, 0);
      }
      #pragma unroll
      for (int ks = 0; ks < 8; ++ks) {
        s16x8 a1 = expand8((rm1[ks] >> shq) & 0xFFu);
        #pragma unroll
        for (int i = 0; i < 4; ++i)
          c1[i] = __builtin_amdgcn_mfma_f32_16x16x32_bf16(a1, wf[i][ks], c1[i], 0, 0, 0);
      }
      if (mt > 0) scan_tile(mt - 1, sc0, m0, sp0, ubits[0][wp]);
      store_c(sc0, c0);
      if (mt > 0) scan_tile(mt - 1, sc1, m1, sp1, ubits[1][wp]);
      store_c(sc1, c1);
    }
    scan_tile(9, sc0, m0, sp0, ubits[0][wp]);
    scan_tile(9, sc1, m1, sp1, ubits[1][wp]);
    __syncthreads();  // bits buf wp complete (both elems)
  }

  // ---- output layer (reads ubits[e][1]): GEMM + mo-scan + softmax (t>50) ----
  {
    s16x8 wo[4][8];
    #pragma unroll
    for (int i = 0; i < 4; ++i) {
      int n = cb + 16 * i;
      bool valid = (n < NOUT);
      #pragma unroll
      for (int ks = 0; ks < 8; ++ks) {
        s16x8 z = {0, 0, 0, 0, 0, 0, 0, 0};
        wo[i][ks] = valid ? *(const s16x8*)(wsb + WS_WO + n * H + ks * 32 + shq) : z;
        asm volatile("" : "+v"(wo[i][ks]));
      }
    }

    float mo0 = 0.0f, mo1 = 0.0f;
    float a00 = 0.f, a01 = 0.f, a02 = 0.f, a03 = 0.f;
    float a10 = 0.f, a11 = 0.f, a12 = 0.f, a13 = 0.f;

    // mo scan: thread tid owns col tid (wave w owns cols 64w..64w+63 ->
    // matches store_c ownership: wave-local, no barrier after store).
    auto moscan = [&](int mt, float* scE, float& mo) {
      if (tid < 208) {
        f32x4* vp = (f32x4*)&scE[tid * CST];
        f32x4 v[4];
        #pragma unroll
        for (int j = 0; j < 4; ++j) v[j] = vp[j];
        #pragma unroll
        for (int r = 0; r < 16; ++r) {
          int t = mt * 16 + r;
          if (t < T_N) {
            float reset = (mo > 1.0f) ? 1.0f : 0.0f;
            mo = 0.9f * mo + v[r >> 2][r & 3] - reset;
            v[r >> 2][r & 3] = mo;
          }
        }
        #pragma unroll
        for (int j = 0; j < 4; ++j) vp[j] = v[j];
      }
    };
    auto softmax_t = [&](int mt, const float* scE, float& s0, float& s1,
                         float& s2, float& s3) {
      #pragma unroll
      for (int rr = 0; rr < 4; ++rr) {
        int r = 4 * wave + rr;
        int t = mt * 16 + r;
        if (t > 50 && t < T_N) {        // wave-uniform
          const float* p = &scE[r];
          float v0 = p[lane * CST];
          float v1 = p[(64 + lane) * CST];
          float v2 = p[(128 + lane) * CST];
          bool has3 = (lane < 8);
          float v3 = has3 ? p[(192 + lane) * CST] : -INFINITY;
          float mx = fmaxf(fmaxf(v0, v1), fmaxf(v2, v3));
          #pragma unroll
          for (int d = 32; d >= 1; d >>= 1) mx = fmaxf(mx, __shfl_xor(mx, d));
          float e0 = __expf(v0 - mx), e1 = __expf(v1 - mx), e2 = __expf(v2 - mx);
          float e3 = has3 ? __expf(v3 - mx) : 0.0f;
          float s = e0 + e1 + e2 + e3;
          #pragma unroll
          for (int d = 32; d >= 1; d >>= 1) s += __shfl_xor(s, d);
          float inv = 1.0f / s;
          s0 += e0 * inv; s1 += e1 * inv; s2 += e2 * inv; s3 += e3 * inv;
        }
      }
    };

    for (int mt = 0; mt < NMT; ++mt) {
      unsigned int rm0[8], rm1[8];
      load_masks(ubits[0][1], mt, rm0);
      load_masks(ubits[1][1], mt, rm1);
      f32x4 c0[4], c1[4];
      #pragma unroll
      for (int i = 0; i < 4; ++i) { f32x4 z = {0.f, 0.f, 0.f, 0.f}; c0[i] = z; c1[i] = z; }
      #pragma unroll
      for (int ks = 0; ks < 8; ++ks) {
        s16x8 a0 = expand8((rm0[ks] >> shq) & 0xFFu);
        s16x8 a1 = expand8((rm1[ks] >> shq) & 0xFFu);
        #pragma unroll
        for (int i = 0; i < 4; ++i) {
          c0[i] = __builtin_amdgcn_mfma_f32_16x16x32_bf16(a0, wo[i][ks], c0[i], 0, 0, 0);
          c1[i] = __builtin_amdgcn_mfma_f32_16x16x32_bf16(a1, wo[i][ks], c1[i], 0, 0, 0);
        }
      }
      __syncthreads();              // prior softmax done reading sc
      store_c(sc0, c0);
      store_c(sc1, c1);
      moscan(mt, sc0, mo0);         // wave-local after wave-local store: no barrier
      moscan(mt, sc1, mo1);
      __syncthreads();              // membranes visible to all waves
      softmax_t(mt, sc0, a00, a01, a02, a03);
      softmax_t(mt, sc1, a10, a11, a12, a13);
    }
    __syncthreads();

    // merge 4 per-wave accumulators per elem via sc, store f32
    sc0[wave * 260 + lane]       = a00;
    sc0[wave * 260 + 64 + lane]  = a01;
    sc0[wave * 260 + 128 + lane] = a02;
    if (lane < 8) sc0[wave * 260 + 192 + lane] = a03;
    sc1[wave * 260 + lane]       = a10;
    sc1[wave * 260 + 64 + lane]  = a11;
    sc1[wave * 260 + 128 + lane] = a12;
    if (lane < 8) sc1[wave * 260 + 192 + lane] = a13;
    __syncthreads();
    if (tid < NOUT) {
      float v0 = 0.f, v1 = 0.f;
      #pragma unroll
      for (int w = 0; w < 4; ++w) {
        v0 += sc0[w * 260 + tid];
        v1 += sc1[w * 260 + tid];
      }
      out[(size_t)(2 * bidx) * NOUT + tid]     = v0;
      out[(size_t)(2 * bidx + 1) * NOUT + tid] = v1;
    }
  }
}

extern "C" void kernel_launch(void* const* d_in, const int* in_sizes, int n_in,
                              void* d_out, int out_size, void* d_ws, size_t ws_size,
                              hipStream_t stream) {
  (void)in_sizes; (void)n_in; (void)ws_size; (void)out_size;
  unsigned short* wsb = (unsigned short*)d_ws;
  cvt_weights<<<256, 256, 0, stream>>>(
      (const float*)d_in[1], (const float*)d_in[3], (const float*)d_in[5],
      (const float*)d_in[7], (const float*)d_in[9], wsb);
  snn_fused<<<1024, 256, 0, stream>>>(
      (const float*)d_in[0], wsb,
      (const float*)d_in[2], (const float*)d_in[4],
      (const float*)d_in[6], (const float*)d_in[8],
      (float*)d_out);
}

// Round 14
// 389.327 us; speedup vs baseline: 1.1588x; 1.0016x over previous
//
#include <hip/hip_runtime.h>
#include <math.h>

// SNN forward, fused. Inputs f32, output f32 [2048][200].
// R14 = R10 (best, 339us) verbatim, plus exactly two scoped changes:
//  (a) hidden layers: e0/e1 MFMA chains interleaved in ONE ks loop
//      (8 concurrent acc chains -> MFMA dependent latency hidden at 2 w/SIMD)
//  (b) OUT phase: 2 barriers/tile (store_c -> moscan is wave-local).
// Config: NE=2 elems/block, 256 thr (4 waves x 64 cols), grid=1024, weights
// pinned (128 regs, AGPR-side), fused scan w/ in-chain ballot (R10 form),
// f32 sc, 72KB LDS, 2 blocks/CU, barrier-free hidden layers.

#define T_N 150
#define DIN 20
#define H 256
#define NOUT 200
#define NMT 10
#define CST 20             // sc col stride (f32): 16 rows + 4 pad
#define SCB 5120           // per-elem sc buffer (f32) = 256 cols * CST
#define XAP 24             // xa row stride (bf16): 20 data + 4 zero pad
#define BW 12              // bits row stride (dwords)
#define BITN (160 * BW + 8)  // per bits buffer (+8 dword tail pad)

#define WS_W1 0
#define WS_W2 5120
#define WS_W3 70656
#define WS_W4 136192
#define WS_WO 201728
#define WS_TOT 252928

typedef short s16x8 __attribute__((ext_vector_type(8)));
typedef float f32x4 __attribute__((ext_vector_type(4)));
typedef unsigned int u32x4 __attribute__((ext_vector_type(4)));

__device__ __forceinline__ unsigned short f2bf(float f) {
  union { float f; unsigned int i; } v; v.f = f;
  unsigned int r = v.i + 0x7FFFu + ((v.i >> 16) & 1u);
  return (unsigned short)(r >> 16);
}

__global__ void cvt_weights(const float* __restrict__ W1, const float* __restrict__ W2,
                            const float* __restrict__ W3, const float* __restrict__ W4,
                            const float* __restrict__ Wo, unsigned short* __restrict__ ws) {
  int idx = blockIdx.x * blockDim.x + threadIdx.x;
  int stride = gridDim.x * blockDim.x;
  for (int i = idx; i < WS_TOT; i += stride) {
    float v;
    if (i < WS_W2)      v = W1[i - WS_W1];
    else if (i < WS_W3) v = W2[i - WS_W2];
    else if (i < WS_W4) v = W3[i - WS_W3];
    else if (i < WS_WO) v = W4[i - WS_W4];
    else                v = Wo[i - WS_WO];
    ws[i] = f2bf(v);
  }
}

// expand 8 spike bits (byte t) -> packed-bf16 x8 fragment (0.0 / 1.0)
__device__ __forceinline__ s16x8 expand8(unsigned int t) {
  unsigned int r2 = t * 0x8001u;   // bit 2j -> pos 2j ; bit 2j+1 -> pos 16+2j
  u32x4 d;
  d[0] = (r2 & 0x00010001u) * 0x3F80u;
  d[1] = (r2 & 0x00040004u) * 0x0FE0u;
  d[2] = (r2 & 0x00100010u) * 0x03F8u;
  d[3] = (r2 & 0x00400040u) * 0x00FEu;
  union { u32x4 u; s16x8 s; } cv; cv.u = d;
  return cv.s;
}

__global__ __launch_bounds__(256, 2) void snn_fused(
    const float* __restrict__ x,             // [2048][150][20] f32
    const unsigned short* __restrict__ wsb,  // bf16 weights (d_ws)
    const float* __restrict__ b1,            // [256] f32
    const float* __restrict__ b2,
    const float* __restrict__ b3,
    const float* __restrict__ b4,
    float* __restrict__ out)                 // [2048][200] f32
{
  __shared__ float sc[2 * SCB];                // 40960 B: per-elem C scratch
  __shared__ unsigned int ubits[2][2][BITN];   // 30976 B: per-elem bits, ping-pong
                                               // total 71936 B -> 2 blocks/CU

  const int tid  = threadIdx.x;
  const int lane = tid & 63;
  const int wave = tid >> 6;    // 0..3
  const int c16  = lane & 15;
  const int quad = lane >> 4;
  const int shq  = quad * 8;
  const int bidx = blockIdx.x;
  const int colw = 64 * wave;   // wave owns cols [64w, 64w+64)
  const int cb   = colw + c16;

  float* sc0 = sc;
  float* sc1 = sc + SCB;
  unsigned short* xa0 = (unsigned short*)&ubits[0][1][0];
  unsigned short* xa1 = (unsigned short*)&ubits[1][1][0];

  auto store_c = [&](float* scE, f32x4* c) {
    #pragma unroll
    for (int i = 0; i < 4; ++i)
      *(f32x4*)&scE[(cb + 16 * i) * CST + quad * 4] = c[i];
  };

  // membrane scan (R10 fused form): 64 lanes own the wave's 64 cols;
  // wave-local sc; in-chain ballot (v_cmp to sgpr, off the fma chain).
  auto scan_tile = [&](int mt, const float* scE, float& m, unsigned int* wb) {
    const f32x4* vp = (const f32x4*)&scE[(colw + lane) * CST];
    f32x4 v[4];
    #pragma unroll
    for (int j = 0; j < 4; ++j) v[j] = vp[j];
    unsigned long long keep = 0ull;
    #pragma unroll
    for (int r = 0; r < 16; ++r) {
      int t = mt * 16 + r;
      if (t < T_N) {  // block-uniform
        float inp = v[r >> 2][r & 3];
        float sel = (m > 1.0f) ? (inp - 1.0f) : inp;
        m = 0.9f * m + sel;
        unsigned long long msk = __ballot(m > 1.0f);
        if (lane == r) keep = msk;
      }
    }
    if (lane < 16)
      *(unsigned long long*)&wb[(mt * 16 + lane) * BW + 2 * wave] = keep;
  };

  auto load_masks = [&](const unsigned int* rb, int mt, unsigned int* rm) {
    const unsigned int* bp = &rb[(mt * 16 + c16) * BW];
    u32x4 a = *(const u32x4*)bp;
    u32x4 b = *(const u32x4*)(bp + 4);
    rm[0] = a[0]; rm[1] = a[1]; rm[2] = a[2]; rm[3] = a[3];
    rm[4] = b[0]; rm[5] = b[1]; rm[6] = b[2]; rm[7] = b[3];
  };

  // ---- init: zero xa regions (k-pad + tail rows), stage x as bf16 ----
  for (int i = tid; i < BITN; i += 256) { ubits[0][1][i] = 0; ubits[1][1][i] = 0; }
  __syncthreads();
  {
    const float* xb0 = x + (size_t)(2 * bidx) * (T_N * DIN);
    const float* xb1 = xb0 + (T_N * DIN);
    for (int i = tid; i < T_N * XAP; i += 256) {
      int t = i / XAP, j = i - t * XAP;
      unsigned short v0 = 0, v1 = 0;
      if (j < DIN) { v0 = f2bf(xb0[t * DIN + j]); v1 = f2bf(xb1[t * DIN + j]); }
      xa0[i] = v0; xa1[i] = v1;
    }
  }

  // ---- layer 1: x @ W1^T (K=20 pad 32) -> ubits[e][0]; barrier-free ----
  {
    s16x8 w1f[4];
    #pragma unroll
    for (int i = 0; i < 4; ++i) {
      int n = cb + 16 * i;
      #pragma unroll
      for (int j = 0; j < 8; ++j) {
        int k = shq + j;
        w1f[i][j] = (k < DIN) ? (short)wsb[WS_W1 + n * DIN + k] : (short)0;
      }
      asm volatile("" : "+v"(w1f[i]));
    }
    float bc[4];
    #pragma unroll
    for (int i = 0; i < 4; ++i) bc[i] = b1[cb + 16 * i];
    float m0 = 0.0f, m1 = 0.0f;
    __syncthreads();  // xa staged
    for (int mt = 0; mt < NMT; ++mt) {
      const s16x8 a0 = *(const s16x8*)&xa0[(mt * 16 + c16) * XAP + shq];
      const s16x8 a1 = *(const s16x8*)&xa1[(mt * 16 + c16) * XAP + shq];
      f32x4 c0[4], c1[4];
      #pragma unroll
      for (int i = 0; i < 4; ++i) {
        f32x4 z = {bc[i], bc[i], bc[i], bc[i]};
        c0[i] = z; c1[i] = z;
      }
      #pragma unroll
      for (int i = 0; i < 4; ++i) {
        c0[i] = __builtin_amdgcn_mfma_f32_16x16x32_bf16(a0, w1f[i], c0[i], 0, 0, 0);
        c1[i] = __builtin_amdgcn_mfma_f32_16x16x32_bf16(a1, w1f[i], c1[i], 0, 0, 0);
      }
      if (mt > 0) scan_tile(mt - 1, sc0, m0, ubits[0][0]);
      store_c(sc0, c0);
      if (mt > 0) scan_tile(mt - 1, sc1, m1, ubits[1][0]);
      store_c(sc1, c1);
    }
    scan_tile(9, sc0, m0, ubits[0][0]);
    scan_tile(9, sc1, m1, ubits[1][0]);
  }
  __syncthreads();  // bits buf 0 complete (both elems)

  // ---- layers 2..4: barrier-free, bits ping-pong per elem ----
  const float* bsl[3] = {b2, b3, b4};
  const int wofs[3] = {WS_W2, WS_W3, WS_W4};
  for (int l = 0; l < 3; ++l) {
    const unsigned short* wl = wsb + wofs[l];
    const int rp = l & 1, wp = rp ^ 1;
    s16x8 wf[4][8];
    #pragma unroll
    for (int i = 0; i < 4; ++i) {
      int n = cb + 16 * i;
      #pragma unroll
      for (int ks = 0; ks < 8; ++ks) {
        wf[i][ks] = *(const s16x8*)(wl + n * H + ks * 32 + shq);
        asm volatile("" : "+v"(wf[i][ks]));
      }
    }
    float bc[4];
    #pragma unroll
    for (int i = 0; i < 4; ++i) bc[i] = bsl[l][cb + 16 * i];
    float m0 = 0.0f, m1 = 0.0f;
    for (int mt = 0; mt < NMT; ++mt) {
      unsigned int rm0[8], rm1[8];
      load_masks(ubits[0][rp], mt, rm0);
      load_masks(ubits[1][rp], mt, rm1);
      f32x4 c0[4], c1[4];
      #pragma unroll
      for (int i = 0; i < 4; ++i) {
        f32x4 z = {bc[i], bc[i], bc[i], bc[i]};
        c0[i] = z; c1[i] = z;
      }
      // (a) interleaved e0/e1: 8 concurrent MFMA acc chains
      #pragma unroll
      for (int ks = 0; ks < 8; ++ks) {
        s16x8 a0 = expand8((rm0[ks] >> shq) & 0xFFu);
        s16x8 a1 = expand8((rm1[ks] >> shq) & 0xFFu);
        #pragma unroll
        for (int i = 0; i < 4; ++i) {
          c0[i] = __builtin_amdgcn_mfma_f32_16x16x32_bf16(a0, wf[i][ks], c0[i], 0, 0, 0);
          c1[i] = __builtin_amdgcn_mfma_f32_16x16x32_bf16(a1, wf[i][ks], c1[i], 0, 0, 0);
        }
      }
      if (mt > 0) scan_tile(mt - 1, sc0, m0, ubits[0][wp]);
      store_c(sc0, c0);
      if (mt > 0) scan_tile(mt - 1, sc1, m1, ubits[1][wp]);
      store_c(sc1, c1);
    }
    scan_tile(9, sc0, m0, ubits[0][wp]);
    scan_tile(9, sc1, m1, ubits[1][wp]);
    __syncthreads();  // bits buf wp complete (both elems)
  }

  // ---- output layer (reads ubits[e][1]): GEMM + mo-scan + softmax (t>50) ----
  {
    s16x8 wo[4][8];
    #pragma unroll
    for (int i = 0; i < 4; ++i) {
      int n = cb + 16 * i;
      bool valid = (n < NOUT);
      #pragma unroll
      for (int ks = 0; ks < 8; ++ks) {
        s16x8 z = {0, 0, 0, 0, 0, 0, 0, 0};
        wo[i][ks] = valid ? *(const s16x8*)(wsb + WS_WO + n * H + ks * 32 + shq) : z;
        asm volatile("" : "+v"(wo[i][ks]));
      }
    }

    float mo0 = 0.0f, mo1 = 0.0f;
    float a00 = 0.f, a01 = 0.f, a02 = 0.f, a03 = 0.f;
    float a10 = 0.f, a11 = 0.f, a12 = 0.f, a13 = 0.f;

    // mo scan: thread tid owns col tid -> same wave that stored it (wave-local)
    auto moscan = [&](int mt, float* scE, float& mo) {
      if (tid < 208) {
        f32x4* vp = (f32x4*)&scE[tid * CST];
        f32x4 v[4];
        #pragma unroll
        for (int j = 0; j < 4; ++j) v[j] = vp[j];
        #pragma unroll
        for (int r = 0; r < 16; ++r) {
          int t = mt * 16 + r;
          if (t < T_N) {
            float reset = (mo > 1.0f) ? 1.0f : 0.0f;
            mo = 0.9f * mo + v[r >> 2][r & 3] - reset;
            v[r >> 2][r & 3] = mo;
          }
        }
        #pragma unroll
        for (int j = 0; j < 4; ++j) vp[j] = v[j];
      }
    };
    auto softmax_t = [&](int mt, const float* scE, float& s0, float& s1,
                         float& s2, float& s3) {
      #pragma unroll
      for (int rr = 0; rr < 4; ++rr) {
        int r = 4 * wave + rr;
        int t = mt * 16 + r;
        if (t > 50 && t < T_N) {        // wave-uniform
          const float* p = &scE[r];
          float v0 = p[lane * CST];
          float v1 = p[(64 + lane) * CST];
          float v2 = p[(128 + lane) * CST];
          bool has3 = (lane < 8);
          float v3 = has3 ? p[(192 + lane) * CST] : -INFINITY;
          float mx = fmaxf(fmaxf(v0, v1), fmaxf(v2, v3));
          #pragma unroll
          for (int d = 32; d >= 1; d >>= 1) mx = fmaxf(mx, __shfl_xor(mx, d));
          float e0 = __expf(v0 - mx), e1 = __expf(v1 - mx), e2 = __expf(v2 - mx);
          float e3 = has3 ? __expf(v3 - mx) : 0.0f;
          float s = e0 + e1 + e2 + e3;
          #pragma unroll
          for (int d = 32; d >= 1; d >>= 1) s += __shfl_xor(s, d);
          float inv = 1.0f / s;
          s0 += e0 * inv; s1 += e1 * inv; s2 += e2 * inv; s3 += e3 * inv;
        }
      }
    };

    for (int mt = 0; mt < NMT; ++mt) {
      unsigned int rm0[8], rm1[8];
      load_masks(ubits[0][1], mt, rm0);
      load_masks(ubits[1][1], mt, rm1);
      f32x4 c0[4], c1[4];
      #pragma unroll
      for (int i = 0; i < 4; ++i) { f32x4 z = {0.f, 0.f, 0.f, 0.f}; c0[i] = z; c1[i] = z; }
      #pragma unroll
      for (int ks = 0; ks < 8; ++ks) {
        s16x8 a0 = expand8((rm0[ks] >> shq) & 0xFFu);
        s16x8 a1 = expand8((rm1[ks] >> shq) & 0xFFu);
        #pragma unroll
        for (int i = 0; i < 4; ++i) {
          c0[i] = __builtin_amdgcn_mfma_f32_16x16x32_bf16(a0, wo[i][ks], c0[i], 0, 0, 0);
          c1[i] = __builtin_amdgcn_mfma_f32_16x16x32_bf16(a1, wo[i][ks], c1[i], 0, 0, 0);
        }
      }
      __syncthreads();              // prior softmax done reading sc
      store_c(sc0, c0);
      store_c(sc1, c1);
      moscan(mt, sc0, mo0);         // (b) wave-local after wave-local store
      moscan(mt, sc1, mo1);
      __syncthreads();              // membranes visible to all waves
      softmax_t(mt, sc0, a00, a01, a02, a03);
      softmax_t(mt, sc1, a10, a11, a12, a13);
    }
    __syncthreads();

    // merge 4 per-wave accumulators per elem via sc, store f32
    sc0[wave * 260 + lane]       = a00;
    sc0[wave * 260 + 64 + lane]  = a01;
    sc0[wave * 260 + 128 + lane] = a02;
    if (lane < 8) sc0[wave * 260 + 192 + lane] = a03;
    sc1[wave * 260 + lane]       = a10;
    sc1[wave * 260 + 64 + lane]  = a11;
    sc1[wave * 260 + 128 + lane] = a12;
    if (lane < 8) sc1[wave * 260 + 192 + lane] = a13;
    __syncthreads();
    if (tid < NOUT) {
      float v0 = 0.f, v1 = 0.f;
      #pragma unroll
      for (int w = 0; w < 4; ++w) {
        v0 += sc0[w * 260 + tid];
        v1 += sc1[w * 260 + tid];
      }
      out[(size_t)(2 * bidx) * NOUT + tid]     = v0;
      out[(size_t)(2 * bidx + 1) * NOUT + tid] = v1;
    }
  }
}

extern "C" void kernel_launch(void* const* d_in, const int* in_sizes, int n_in,
                              void* d_out, int out_size, void* d_ws, size_t ws_size,
                              hipStream_t stream) {
  (void)in_sizes; (void)n_in; (void)ws_size; (void)out_size;
  unsigned short* wsb = (unsigned short*)d_ws;
  cvt_weights<<<256, 256, 0, stream>>>(
      (const float*)d_in[1], (const float*)d_in[3], (const float*)d_in[5],
      (const float*)d_in[7], (const float*)d_in[9], wsb);
  snn_fused<<<1024, 256, 0, stream>>>(
      (const float*)d_in[0], wsb,
      (const float*)d_in[2], (const float*)d_in[4],
      (const float*)d_in[6], (const float*)d_in[8],
      (float*)d_out);
}

// Round 15
// 310.882 us; speedup vs baseline: 1.4512x; 1.2523x over previous
//
#include <hip/hip_runtime.h>
#include <math.h>

// SNN forward, fused. Inputs f32, output f32 [2048][200].
// R15: FP8(e4m3) weights for layers 2-5 -> B-frag 2 regs -> 64-col weight set
// is 64 VGPRs (was 128 bf16) -> whole wave ~120 regs -> 4 waves/SIMD,
// 4 blocks/CU (NE=1, 36KB LDS), grid=2048 = 2 exact rounds. Spikes are EXACT
// in e4m3 (1.0=0x38); only weights quantize (RNE). Layer 1 stays bf16.
// Structure = R9/R14: barrier-free hidden layers, fused scan, bits ping-pong.

#define T_N 150
#define DIN 20
#define H 256
#define NOUT 200
#define NMT 10
#define CST 20             // sc col stride (f32): 16 rows + 4 pad
#define SCB 5120           // sc size (f32) = 256 cols * CST
#define XAP 24             // xa row stride (bf16 shorts) = BW dwords
#define BW 12              // bits row stride (dwords)
#define BITN (160 * BW + 8)

// d_ws layout: [0,5120) shorts = bf16 W1; then fp8 bytes W2,W3,W4,Wo
#define N_W1 5120
#define F8_W2 0
#define F8_W3 65536
#define F8_W4 131072
#define F8_WO 196608
#define F8_TOT 247808

typedef short s16x8 __attribute__((ext_vector_type(8)));
typedef float f32x4 __attribute__((ext_vector_type(4)));
typedef unsigned int u32x4 __attribute__((ext_vector_type(4)));

__device__ __forceinline__ unsigned short f2bf(float f) {
  union { float f; unsigned int i; } v; v.f = f;
  unsigned int r = v.i + 0x7FFFu + ((v.i >> 16) & 1u);
  return (unsigned short)(r >> 16);
}

// f32 -> OCP e4m3 (RNE, handles subnormals; inputs |f| <= 0.25, no sat needed)
__device__ __forceinline__ unsigned char f2e4m3(float f) {
  union { float f; unsigned u; } v; v.f = f;
  unsigned s = (v.u >> 24) & 0x80u;
  unsigned mag = v.u & 0x7FFFFFFFu;
  if (mag == 0) return (unsigned char)s;
  int e = (int)(mag >> 23) - 127;
  unsigned man = mag & 0x7FFFFFu;
  unsigned q;
  if (e >= -6) {
    unsigned r = man + 0x7FFFFu + ((man >> 20) & 1u);
    if (r >= 0x800000u) { e += 1; r -= 0x800000u; }
    q = ((unsigned)(e + 7) << 3) | (r >> 20);
  } else {
    unsigned mant = 0x800000u | man;
    int sh = 14 - e;                 // value*512 = mant >> sh (fixed point)
    if (sh > 31) q = 0;
    else {
      unsigned fl = mant >> sh;
      unsigned rem = mant & ((1u << sh) - 1u);
      unsigned half = 1u << (sh - 1);
      q = fl + ((rem > half || (rem == half && (fl & 1))) ? 1u : 0u);
    }
  }
  return (unsigned char)(s | q);
}

__global__ void cvt_weights(const float* __restrict__ W1, const float* __restrict__ W2,
                            const float* __restrict__ W3, const float* __restrict__ W4,
                            const float* __restrict__ Wo, unsigned short* __restrict__ ws) {
  int idx = blockIdx.x * blockDim.x + threadIdx.x;
  int stride = gridDim.x * blockDim.x;
  for (int i = idx; i < N_W1; i += stride) ws[i] = f2bf(W1[i]);
  unsigned char* f8 = (unsigned char*)(ws + N_W1);
  for (int i = idx; i < F8_TOT; i += stride) {
    float v;
    if (i < F8_W3)      v = W2[i - F8_W2];
    else if (i < F8_W4) v = W3[i - F8_W3];
    else if (i < F8_WO) v = W4[i - F8_W4];
    else                v = Wo[i - F8_WO];
    f8[i] = f2e4m3(v);
  }
}

// expand 8 spike bits -> 8 fp8 e4m3 bytes (0x00 / 0x38) packed in a long.
// bit j -> byte j (dword0 = bits 0-3, dword1 = bits 4-7).
__device__ __forceinline__ long expand8_f8(unsigned t) {
  unsigned lo = ((t & 0xFu) * 0x204081u) & 0x01010101u;
  unsigned hi = ((t >> 4) * 0x204081u) & 0x01010101u;
  lo *= 0x38u; hi *= 0x38u;
  union { unsigned u[2]; long l; } cv; cv.u[0] = lo; cv.u[1] = hi;
  return cv.l;
}

__global__ __launch_bounds__(256, 4) void snn_fused(
    const float* __restrict__ x,             // [2048][150][20] f32
    const unsigned short* __restrict__ wsb,  // d_ws: bf16 W1 + fp8 W2..Wo
    const float* __restrict__ b1,            // [256] f32
    const float* __restrict__ b2,
    const float* __restrict__ b3,
    const float* __restrict__ b4,
    float* __restrict__ out)                 // [2048][200] f32
{
  __shared__ float sc[SCB];                  // 20480 B: col-major C scratch
  __shared__ unsigned int ubits[2][BITN];    // 15424 B: spike bits, ping-pong
                                             // total 35904 B -> 4 blocks/CU

  const int tid  = threadIdx.x;
  const int lane = tid & 63;
  const int wave = tid >> 6;    // 0..3
  const int c16  = lane & 15;
  const int quad = lane >> 4;
  const int shq  = quad * 8;
  const int bidx = blockIdx.x;
  const int colw = 64 * wave;   // wave owns cols [64w, 64w+64)
  const int cb   = colw + c16;

  const unsigned char* f8 = (const unsigned char*)(wsb + N_W1);
  unsigned short* xa = (unsigned short*)&ubits[1][0];

  auto store_c = [&](f32x4* c) {
    #pragma unroll
    for (int i = 0; i < 4; ++i)
      *(f32x4*)&sc[(cb + 16 * i) * CST + quad * 4] = c[i];
  };

  // fused membrane scan (R10/R14 form): 64 lanes own the wave's 64 cols
  auto scan_tile = [&](int mt, float& m, unsigned int* wb) {
    const f32x4* vp = (const f32x4*)&sc[(colw + lane) * CST];
    f32x4 v[4];
    #pragma unroll
    for (int j = 0; j < 4; ++j) v[j] = vp[j];
    unsigned long long keep = 0ull;
    #pragma unroll
    for (int r = 0; r < 16; ++r) {
      int t = mt * 16 + r;
      if (t < T_N) {  // block-uniform
        float inp = v[r >> 2][r & 3];
        float sel = (m > 1.0f) ? (inp - 1.0f) : inp;
        m = 0.9f * m + sel;
        unsigned long long msk = __ballot(m > 1.0f);
        if (lane == r) keep = msk;
      }
    }
    if (lane < 16)
      *(unsigned long long*)&wb[(mt * 16 + lane) * BW + 2 * wave] = keep;
  };

  auto load_masks = [&](const unsigned int* rb, int mt, unsigned int* rm) {
    const unsigned int* bp = &rb[(mt * 16 + c16) * BW];
    u32x4 a = *(const u32x4*)bp;
    u32x4 b = *(const u32x4*)(bp + 4);
    rm[0] = a[0]; rm[1] = a[1]; rm[2] = a[2]; rm[3] = a[3];
    rm[4] = b[0]; rm[5] = b[1]; rm[6] = b[2]; rm[7] = b[3];
  };

  // ---- init: zero both bits buffers; stage x as bf16 into xa (=ubits[1]) ----
  for (int i = tid; i < 2 * BITN; i += 256) ((unsigned int*)ubits)[i] = 0;
  __syncthreads();
  {
    const float* xb = x + (size_t)bidx * (T_N * DIN);
    for (int i = tid; i < T_N * DIN; i += 256) {
      int t = i / DIN, j = i - t * DIN;
      xa[t * XAP + j] = f2bf(xb[i]);
    }
  }

  // ---- layer 1 (bf16): x @ W1^T (K=20 pad 32) -> ubits[0]; barrier-free ----
  {
    s16x8 w1f[4];
    #pragma unroll
    for (int i = 0; i < 4; ++i) {
      int n = cb + 16 * i;
      #pragma unroll
      for (int j = 0; j < 8; ++j) {
        int k = shq + j;
        w1f[i][j] = (k < DIN) ? (short)wsb[n * DIN + k] : (short)0;
      }
      asm volatile("" : "+v"(w1f[i]));
    }
    float bc[4];
    #pragma unroll
    for (int i = 0; i < 4; ++i) bc[i] = b1[cb + 16 * i];
    float m = 0.0f;
    __syncthreads();  // xa staged
    for (int mt = 0; mt < NMT; ++mt) {
      const s16x8 a1 = *(const s16x8*)&xa[(mt * 16 + c16) * XAP + shq];
      f32x4 c[4];
      #pragma unroll
      for (int i = 0; i < 4; ++i) { f32x4 z = {bc[i], bc[i], bc[i], bc[i]}; c[i] = z; }
      #pragma unroll
      for (int i = 0; i < 4; ++i)
        c[i] = __builtin_amdgcn_mfma_f32_16x16x32_bf16(a1, w1f[i], c[i], 0, 0, 0);
      if (mt > 0) scan_tile(mt - 1, m, ubits[0]);
      store_c(c);
    }
    scan_tile(9, m, ubits[0]);
  }
  __syncthreads();  // bits[0] complete (xa dead from here)

  // ---- layers 2..4 (fp8 weights): barrier-free, bits ping-pong ----
  const float* bsl[3] = {b2, b3, b4};
  const int wofs[3] = {F8_W2, F8_W3, F8_W4};
  for (int l = 0; l < 3; ++l) {
    const unsigned char* wl = f8 + wofs[l];
    const int rp = l & 1, wp = rp ^ 1;
    long wf[4][8];
    #pragma unroll
    for (int i = 0; i < 4; ++i) {
      int n = cb + 16 * i;
      #pragma unroll
      for (int ks = 0; ks < 8; ++ks) {
        wf[i][ks] = *(const long*)(wl + n * H + ks * 32 + shq);
        asm volatile("" : "+v"(wf[i][ks]));
      }
    }
    float bc[4];
    #pragma unroll
    for (int i = 0; i < 4; ++i) bc[i] = bsl[l][cb + 16 * i];
    float m = 0.0f;
    for (int mt = 0; mt < NMT; ++mt) {
      unsigned int rm[8];
      load_masks(ubits[rp], mt, rm);
      f32x4 c[4];
      #pragma unroll
      for (int i = 0; i < 4; ++i) { f32x4 z = {bc[i], bc[i], bc[i], bc[i]}; c[i] = z; }
      #pragma unroll
      for (int ks = 0; ks < 8; ++ks) {
        long a = expand8_f8((rm[ks] >> shq) & 0xFFu);
        #pragma unroll
        for (int i = 0; i < 4; ++i)
          c[i] = __builtin_amdgcn_mfma_f32_16x16x32_fp8_fp8(a, wf[i][ks], c[i], 0, 0, 0);
      }
      if (mt > 0) scan_tile(mt - 1, m, ubits[wp]);
      store_c(c);
    }
    scan_tile(9, m, ubits[wp]);
    __syncthreads();  // bits[wp] complete
  }

  // ---- output layer (fp8, reads ubits[1]): GEMM + mo-scan + softmax ----
  {
    long wo[4][8];
    #pragma unroll
    for (int i = 0; i < 4; ++i) {
      int n = cb + 16 * i;
      bool valid = (n < NOUT);
      #pragma unroll
      for (int ks = 0; ks < 8; ++ks) {
        wo[i][ks] = valid ? *(const long*)(f8 + F8_WO + n * H + ks * 32 + shq) : 0L;
        asm volatile("" : "+v"(wo[i][ks]));
      }
    }

    float mo = 0.0f;
    float a0 = 0.f, a1 = 0.f, a2 = 0.f, a3 = 0.f;

    auto moscan = [&](int mt) {
      if (tid < 208) {
        f32x4* vp = (f32x4*)&sc[tid * CST];
        f32x4 v[4];
        #pragma unroll
        for (int j = 0; j < 4; ++j) v[j] = vp[j];
        #pragma unroll
        for (int r = 0; r < 16; ++r) {
          int t = mt * 16 + r;
          if (t < T_N) {
            float reset = (mo > 1.0f) ? 1.0f : 0.0f;
            mo = 0.9f * mo + v[r >> 2][r & 3] - reset;
            v[r >> 2][r & 3] = mo;
          }
        }
        #pragma unroll
        for (int j = 0; j < 4; ++j) vp[j] = v[j];
      }
    };
    auto softmax_t = [&](int mt) {
      #pragma unroll
      for (int rr = 0; rr < 4; ++rr) {
        int r = 4 * wave + rr;
        int t = mt * 16 + r;
        if (t > 50 && t < T_N) {        // wave-uniform
          const float* p = &sc[r];
          float v0 = p[lane * CST];
          float v1 = p[(64 + lane) * CST];
          float v2 = p[(128 + lane) * CST];
          bool has3 = (lane < 8);
          float v3 = has3 ? p[(192 + lane) * CST] : -INFINITY;
          float mx = fmaxf(fmaxf(v0, v1), fmaxf(v2, v3));
          #pragma unroll
          for (int d = 32; d >= 1; d >>= 1) mx = fmaxf(mx, __shfl_xor(mx, d));
          float e0 = __expf(v0 - mx), e1 = __expf(v1 - mx), e2 = __expf(v2 - mx);
          float e3 = has3 ? __expf(v3 - mx) : 0.0f;
          float s = e0 + e1 + e2 + e3;
          #pragma unroll
          for (int d = 32; d >= 1; d >>= 1) s += __shfl_xor(s, d);
          float inv = 1.0f / s;
          a0 += e0 * inv; a1 += e1 * inv; a2 += e2 * inv; a3 += e3 * inv;
        }
      }
    };

    for (int mt = 0; mt < NMT; ++mt) {
      unsigned int rm[8];
      load_masks(ubits[1], mt, rm);
      f32x4 c[4];
      #pragma unroll
      for (int i = 0; i < 4; ++i) { f32x4 z = {0.f, 0.f, 0.f, 0.f}; c[i] = z; }
      #pragma unroll
      for (int ks = 0; ks < 8; ++ks) {
        long a = expand8_f8((rm[ks] >> shq) & 0xFFu);
        #pragma unroll
        for (int i = 0; i < 4; ++i)
          c[i] = __builtin_amdgcn_mfma_f32_16x16x32_fp8_fp8(a, wo[i][ks], c[i], 0, 0, 0);
      }
      __syncthreads();              // prior softmax done reading sc
      store_c(c);
      moscan(mt);                   // wave-local after wave-local store
      __syncthreads();              // membranes visible to all waves
      softmax_t(mt);
    }
    __syncthreads();

    // merge 4 per-wave accumulators via sc, store f32
    sc[wave * 260 + lane]       = a0;
    sc[wave * 260 + 64 + lane]  = a1;
    sc[wave * 260 + 128 + lane] = a2;
    if (lane < 8) sc[wave * 260 + 192 + lane] = a3;
    __syncthreads();
    if (tid < NOUT) {
      float v = sc[tid] + sc[260 + tid] + sc[520 + tid] + sc[780 + tid];
      out[(size_t)bidx * NOUT + tid] = v;
    }
  }
}

extern "C" void kernel_launch(void* const* d_in, const int* in_sizes, int n_in,
                              void* d_out, int out_size, void* d_ws, size_t ws_size,
                              hipStream_t stream) {
  (void)in_sizes; (void)n_in; (void)ws_size; (void)out_size;
  unsigned short* wsb = (unsigned short*)d_ws;
  cvt_weights<<<256, 256, 0, stream>>>(
      (const float*)d_in[1], (const float*)d_in[3], (const float*)d_in[5],
      (const float*)d_in[7], (const float*)d_in[9], wsb);
  snn_fused<<<2048, 256, 0, stream>>>(
      (const float*)d_in[0], wsb,
      (const float*)d_in[2], (const float*)d_in[4],
      (const float*)d_in[6], (const float*)d_in[8],
      (float*)d_out);
}